// Round 8
// baseline (182.237 us; speedup 1.0000x reference)
//
#include <hip/hip_runtime.h>
#include <stdint.h>

typedef unsigned short u16;
typedef __attribute__((__ext_vector_type__(4))) float f32x4;
typedef __attribute__((__ext_vector_type__(8))) __bf16 bf16x8;
typedef __attribute__((__ext_vector_type__(4))) unsigned short u16x4;
typedef __attribute__((__ext_vector_type__(8))) unsigned short u16x8;

#define DEV static __device__ __forceinline__

DEV u16 f2b(float f) {
  union { float f; unsigned u; } v; v.f = f;
  unsigned r = v.u + 0x7FFFu + ((v.u >> 16) & 1u);   // RNE to bf16
  return (u16)(r >> 16);
}

typedef const __attribute__((address_space(1))) void* gas_t;
typedef __attribute__((address_space(3))) void* las_t;

// async global->LDS, 16B per lane; LDS dest = wave-uniform base + lane*16
DEV void gl_lds16(const void* g, void* l) {
  __builtin_amdgcn_global_load_lds((gas_t)(uintptr_t)g, (las_t)(uint32_t)(uintptr_t)l,
                                   16, 0, 0);
}

// ---------------- fp32 -> bf16 convert ----------------
__global__ void cvt4(const float* __restrict__ s, u16* __restrict__ d, int n4) {
  const int i = blockIdx.x * 256 + threadIdx.x;
  if (i >= n4) return;
  const float4 f = reinterpret_cast<const float4*>(s)[i];
  u16x4 o;
  o.x = f2b(f.x); o.y = f2b(f.y); o.z = f2b(f.z); o.w = f2b(f.w);
  reinterpret_cast<u16x4*>(d)[i] = o;
}

// fused weight convert: Wq|Wk|Wv -> Wqkv (stacked), Wo -> Wob
__global__ void cvtW(const float* __restrict__ Wq, const float* __restrict__ Wk,
                     const float* __restrict__ Wv, const float* __restrict__ Wo,
                     u16* __restrict__ Wqkv, u16* __restrict__ Wob) {
  const int bid = blockIdx.x, sel = bid >> 10;
  const int i = (bid & 1023) * 256 + threadIdx.x;
  const float* s = sel == 0 ? Wq : sel == 1 ? Wk : sel == 2 ? Wv : Wo;
  u16* d = (sel == 3) ? Wob : Wqkv + sel * 1048576;
  const float4 f = reinterpret_cast<const float4*>(s)[i];
  u16x4 o;
  o.x = f2b(f.x); o.y = f2b(f.y); o.z = f2b(f.z); o.w = f2b(f.w);
  reinterpret_cast<u16x4*>(d)[i] = o;
}

// ---------------- QKV GEMM: 256x256 tile, 8 waves, BK=64 ----------------
// C[8192x3072] = A[8192x1024] * B[3072x1024]^T. Per wave: 128x64 output
// (acc[8][4]). Double-buffered 128KiB LDS; counted-vmcnt schedule:
//   gate { vmcnt(8); s_barrier }  -> tile T staged, T+1 in flight
//   compute 64 MFMA/wave (2 ks-halves x 4 nf, setprio around clusters)
//   release s_barrier; stage(T+2 -> just-freed buffer)
// T2 XOR swizzle on LDS rows (pre-swizzled global source, rule #21).
// Epilogue: Q (pre-scaled 1/sqrt(64)*log2e) + K scatter; V via full-LDS
// 256x256 bounce transpose -> Vt[b,h,d,n'] (PV k-permuted), 16B stores.
__global__ __launch_bounds__(512, 2) void gemm256(
    const u16* __restrict__ A, const u16* __restrict__ B,
    u16* __restrict__ Qo, u16* __restrict__ Ko, u16* __restrict__ Vo)
{
  __shared__ u16 smem[65536];   // 2 x (A 256x64 + B 256x64) = 128 KiB
  const int K = 1024;
  const int nwg = gridDim.x;    // 384
  const int bid = blockIdx.x;
  const int swz = (bid & 7) * (nwg >> 3) + (bid >> 3);   // XCD-contiguous
  const int tm = swz / 12, tn = swz % 12;
  const int tid = threadIdx.x, wid = tid >> 6, lane = tid & 63;
  const int wm = wid >> 2, wn = wid & 3;
  const int lr = lane & 15, lk = lane >> 4;

  const f32x4 fz = {0.f, 0.f, 0.f, 0.f};
  f32x4 acc[8][4];
#pragma unroll
  for (int i = 0; i < 8; i++)
#pragma unroll
    for (int j = 0; j < 4; j++) acc[i][j] = fz;

  const u16* Ab = A + (size_t)tm * 256 * K;
  const u16* Bb = B + (size_t)tn * 256 * K;

  // stage K-tile kt (64 cols) into buffer buf: 2048 chunks of 16B per operand,
  // chunk c -> row c>>3, slot c&7; source col pre-swizzled by row&7.
  auto stage = [&](int kt, int buf) {
    u16* As = smem + buf * 32768;
    u16* Bs = As + 16384;
#pragma unroll
    for (int i = 0; i < 4; i++) {
      const int c = tid + 512 * i;
      const int r = c >> 3;
      const int col = kt * 64 + (((c & 7) ^ (r & 7)) * 8);
      u16* dstA = &As[(i * 512 + wid * 64) * 8];
      u16* dstB = &Bs[(i * 512 + wid * 64) * 8];
      gl_lds16(Ab + (size_t)r * K + col, dstA);
      gl_lds16(Bb + (size_t)r * K + col, dstB);
    }
  };

  stage(0, 0);
  stage(1, 1);
  for (int T = 0; T < 16; T++) {
    if (T < 15) asm volatile("s_waitcnt vmcnt(8)" ::: "memory");
    else        asm volatile("s_waitcnt vmcnt(0)" ::: "memory");
    asm volatile("s_barrier" ::: "memory");
    const u16* As = smem + (T & 1) * 32768;
    const u16* Bs = As + 16384;
#pragma unroll
    for (int ks = 0; ks < 2; ks++) {
      bf16x8 af[8];
#pragma unroll
      for (int mf = 0; mf < 8; mf++) {
        const int row = wm * 128 + mf * 16 + lr;
        af[mf] = *reinterpret_cast<const bf16x8*>(
            &As[row * 64 + (((ks * 4 + lk) ^ (row & 7)) * 8)]);
      }
#pragma unroll
      for (int nf = 0; nf < 4; nf++) {
        const int row = wn * 64 + nf * 16 + lr;
        const bf16x8 bfr = *reinterpret_cast<const bf16x8*>(
            &Bs[row * 64 + (((ks * 4 + lk) ^ (row & 7)) * 8)]);
        __builtin_amdgcn_s_setprio(1);
#pragma unroll
        for (int mf = 0; mf < 8; mf++)
          acc[mf][nf] = __builtin_amdgcn_mfma_f32_16x16x32_bf16(af[mf], bfr, acc[mf][nf], 0, 0, 0);
        __builtin_amdgcn_s_setprio(0);
      }
    }
    asm volatile("s_barrier" ::: "memory");
    if (T + 2 < 16) stage(T + 2, T & 1);
  }

  const int mat = tn >> 2;            // 0=Q 1=K 2=V (block-uniform)
  const int b = tm >> 3, n0 = (tm & 7) * 256;
  if (mat < 2) {
    u16* Mo = (mat == 0) ? Qo : Ko;
    const float qs = (mat == 0) ? 0.18033688f : 1.0f;  // Q: 1/sqrt(64)*log2e
#pragma unroll
    for (int mf = 0; mf < 8; mf++) {
#pragma unroll
      for (int nf = 0; nf < 4; nf++) {
        const int e = (tn & 3) * 256 + wn * 64 + nf * 16 + lr;
        const int h = e >> 6, d = e & 63;
#pragma unroll
        for (int r = 0; r < 4; r++) {
          const int n = n0 + wm * 128 + mf * 16 + lk * 4 + r;
          Mo[((b * 16 + h) * 2048 + n) * 64 + d] = f2b(acc[mf][nf][r] * qs);
        }
      }
    }
  } else {
    // ---- V: bounce through full LDS (256x256 transpose), 16B stores ----
    __syncthreads();   // K-loop's final barrier already passed; belt+braces
#pragma unroll
    for (int mf = 0; mf < 8; mf++) {
#pragma unroll
      for (int nf = 0; nf < 4; nf++) {
        const int e = wn * 64 + nf * 16 + lr;       // local channel 0..255
        const int m4 = wm * 128 + mf * 16 + lk * 4; // local row chunk
        u16x4 pk;
#pragma unroll
        for (int r = 0; r < 4; r++) pk[r] = f2b(acc[mf][nf][r]);
        *reinterpret_cast<u16x4*>(&smem[e * 256 + (m4 ^ ((e & 7) << 3))]) = pk;
      }
    }
    __syncthreads();
    const int e = tid >> 1, half = tid & 1;
    const int h = ((tn & 3) << 2) + (e >> 6), d = e & 63;
    u16* Vrow = Vo + ((size_t)((b * 16 + h) * 64 + d)) * 2048 + n0;
    const int xe = (e & 7) << 3;
#pragma unroll
    for (int s = 0; s < 16; s++) {
      // dest chunk npl -> source n chunk (inverse PV k-perm):
      // np = g*32 + l2*8 + h1*4 + j  <=  n = g*32 + h1*16 + l2*4 + j
      const int npl = half * 128 + s * 8;
      const int nA = (npl & ~31) | ((npl >> 1) & 12);
      const u16x4 a = *reinterpret_cast<const u16x4*>(&smem[e * 256 + (nA ^ xe)]);
      const u16x4 bq = *reinterpret_cast<const u16x4*>(&smem[e * 256 + ((nA + 16) ^ xe)]);
      u16x8 o;
#pragma unroll
      for (int r = 0; r < 4; r++) { o[r] = a[r]; o[4 + r] = bq[r]; }
      *reinterpret_cast<u16x8*>(&Vrow[npl]) = o;
    }
  }
}

// ---------------- out-proj GEMM (unchanged 128x128 structure) ------------
__global__ __launch_bounds__(256, 2) void gemm_out(
    const u16* __restrict__ A, const u16* __restrict__ B, int K, int tiles_n,
    float* __restrict__ Fo, const float* __restrict__ bias, int N)
{
  __shared__ u16 smem[24576];   // 3 x (As 4096 + Bs 4096)
  const int nwg = gridDim.x;
  const int bid = blockIdx.x;
  const int swz = (bid & 7) * (nwg >> 3) + (bid >> 3);
  const int tm = swz / tiles_n, tn = swz % tiles_n;
  const int tid = threadIdx.x, wid = tid >> 6, lane = tid & 63;
  const int wr = wid >> 1, wc = wid & 1;
  const int lr = lane & 15, lk = lane >> 4;

  const f32x4 fz = {0.f, 0.f, 0.f, 0.f};
  f32x4 acc[4][4];
#pragma unroll
  for (int i = 0; i < 4; i++)
#pragma unroll
    for (int j = 0; j < 4; j++) acc[i][j] = fz;

  const u16* Ab = A + (size_t)tm * 128 * K;
  const u16* Bb = B + (size_t)tn * 128 * K;

  const int ca = tid, cb2 = tid + 256;
  const int ra = ca >> 2,  ka = ((ca  & 3) ^ ((ra  >> 1) & 3)) * 8;
  const int rb = cb2 >> 2, kb = ((cb2 & 3) ^ ((rb  >> 1) & 3)) * 8;

  auto stage = [&](int k0, int buf) {
    u16* As = smem + buf * 8192;
    u16* Bs = As + 4096;
    gl_lds16(Ab + (size_t)ra * K + k0 + ka, &As[wid * 512]);
    gl_lds16(Ab + (size_t)rb * K + k0 + kb, &As[2048 + wid * 512]);
    gl_lds16(Bb + (size_t)ra * K + k0 + ka, &Bs[wid * 512]);
    gl_lds16(Bb + (size_t)rb * K + k0 + kb, &Bs[2048 + wid * 512]);
  };

  const int nk = K >> 5;
  stage(0, 0);
  stage(32, 1);
  for (int t = 0; t < nk; t++) {
    const int cur = t % 3;
    if (t < nk - 1) asm volatile("s_waitcnt vmcnt(4)" ::: "memory");
    else            asm volatile("s_waitcnt vmcnt(0)" ::: "memory");
    asm volatile("s_barrier" ::: "memory");
    if (t + 2 < nk) stage((t + 2) * 32, (t + 2) % 3);
    const u16* As = smem + cur * 8192;
    const u16* Bs = As + 4096;
    bf16x8 af[4], bf[4];
#pragma unroll
    for (int i = 0; i < 4; i++) {
      const int row = wr * 64 + i * 16 + lr;
      af[i] = *reinterpret_cast<const bf16x8*>(&As[row * 32 + (lk ^ ((row >> 1) & 3)) * 8]);
    }
#pragma unroll
    for (int j = 0; j < 4; j++) {
      const int row = wc * 64 + j * 16 + lr;
      bf[j] = *reinterpret_cast<const bf16x8*>(&Bs[row * 32 + (lk ^ ((row >> 1) & 3)) * 8]);
    }
#pragma unroll
    for (int i = 0; i < 4; i++)
#pragma unroll
      for (int j = 0; j < 4; j++)
        acc[i][j] = __builtin_amdgcn_mfma_f32_16x16x32_bf16(af[i], bf[j], acc[i][j], 0, 0, 0);
  }

  const int row0 = tm * 128 + wr * 64;
#pragma unroll
  for (int i = 0; i < 4; i++) {
#pragma unroll
    for (int j = 0; j < 4; j++) {
      const int col = tn * 128 + wc * 64 + j * 16 + lr;
      const float bv = bias[col];
#pragma unroll
      for (int r = 0; r < 4; r++) {
        const int m = row0 + i * 16 + lk * 4 + r;
        Fo[(size_t)m * N + col] = acc[i][j][r] + bv;
      }
    }
  }
}

// ---------------- flash attention (swapped-QK, max-free softmax) ----------
__global__ __launch_bounds__(256, 2) void attn_fwd(
    const u16* __restrict__ Q, const u16* __restrict__ K, const u16* __restrict__ Vt,
    u16* __restrict__ O)
{
  __shared__ u16 Ks[2][64 * 64];
  __shared__ u16 Vs[2][64 * 64];
  const int bh = blockIdx.x >> 4, qt = blockIdx.x & 15;
  const int tid = threadIdx.x, w = tid >> 6, lane = tid & 63;
  const int lr = lane & 15, lk = lane >> 4;
  const u16* Qp = Q + ((size_t)bh * 2048 + qt * 128) * 64;
  const u16* Kp = K + (size_t)bh * 2048 * 64;
  const u16* Vp = Vt + (size_t)bh * 64 * 2048;

  bf16x8 qfr[2][2];
#pragma unroll
  for (int qf = 0; qf < 2; qf++)
#pragma unroll
    for (int kk = 0; kk < 2; kk++)
      qfr[qf][kk] = *reinterpret_cast<const bf16x8*>(
          &Qp[(w * 32 + qf * 16 + lr) * 64 + kk * 32 + lk * 8]);

  const f32x4 fz = {0.f, 0.f, 0.f, 0.f};
  f32x4 oacc[2][4];
  float ls[2] = {0.f, 0.f};
#pragma unroll
  for (int qf = 0; qf < 2; qf++)
#pragma unroll
    for (int df = 0; df < 4; df++) oacc[qf][df] = fz;

  auto stage = [&](int kt, int buf) {
#pragma unroll
    for (int i = 0; i < 2; i++) {
      const int c = tid + 256 * i;
      const int r = c >> 3, ss = ((c & 7) ^ (r & 7)) * 8;
      gl_lds16(Kp + (size_t)(kt * 64 + r) * 64 + ss, &Ks[buf][w * 512 + i * 2048]);
      gl_lds16(Vp + (size_t)r * 2048 + kt * 64 + ss, &Vs[buf][w * 512 + i * 2048]);
    }
  };

  stage(0, 0);
  for (int kt = 0; kt < 32; kt++) {
    const int cur = kt & 1;
    asm volatile("s_waitcnt vmcnt(0)" ::: "memory");
    __syncthreads();
    if (kt < 31) stage(kt + 1, cur ^ 1);

    // S^T = K Q^T : lane holds S[q=lr][k = kf*16 + 4*lk + r]
    f32x4 sacc[2][4];
#pragma unroll
    for (int qf = 0; qf < 2; qf++)
#pragma unroll
      for (int kf = 0; kf < 4; kf++) sacc[qf][kf] = fz;
    __builtin_amdgcn_s_setprio(1);
#pragma unroll
    for (int kk = 0; kk < 2; kk++) {
#pragma unroll
      for (int kf = 0; kf < 4; kf++) {
        const int row = kf * 16 + lr;
        bf16x8 kfr = *reinterpret_cast<const bf16x8*>(
            &Ks[cur][row * 64 + (((kk * 4 + lk) ^ (row & 7)) * 8)]);
        sacc[0][kf] = __builtin_amdgcn_mfma_f32_16x16x32_bf16(kfr, qfr[0][kk], sacc[0][kf], 0, 0, 0);
        sacc[1][kf] = __builtin_amdgcn_mfma_f32_16x16x32_bf16(kfr, qfr[1][kk], sacc[1][kf], 0, 0, 0);
      }
    }
    __builtin_amdgcn_s_setprio(0);

    // max-free softmax: p = exp2(s); per-lane partial sums
    bf16x8 pa[2][2];
#pragma unroll
    for (int qf = 0; qf < 2; qf++) {
      float lsum = 0.f;
#pragma unroll
      for (int kf = 0; kf < 4; kf++)
#pragma unroll
        for (int r = 0; r < 4; r++) {
          const float pv = __builtin_amdgcn_exp2f(sacc[qf][kf][r]);
          sacc[qf][kf][r] = pv;
          lsum += pv;
        }
      ls[qf] += lsum;
#pragma unroll
      for (int kk = 0; kk < 2; kk++)
#pragma unroll
        for (int j = 0; j < 4; j++) {
          pa[qf][kk][j]     = (__bf16)sacc[qf][2 * kk][j];
          pa[qf][kk][4 + j] = (__bf16)sacc[qf][2 * kk + 1][j];
        }
    }

    // O += P V ; V columns pre-permuted in global so fragment = one b128
    __builtin_amdgcn_s_setprio(1);
#pragma unroll
    for (int df = 0; df < 4; df++) {
      const int d = df * 16 + lr;
#pragma unroll
      for (int kk = 0; kk < 2; kk++) {
        bf16x8 vfr = *reinterpret_cast<const bf16x8*>(
            &Vs[cur][d * 64 + (((kk * 4 + lk) ^ (d & 7)) * 8)]);
        oacc[0][df] = __builtin_amdgcn_mfma_f32_16x16x32_bf16(pa[0][kk], vfr, oacc[0][df], 0, 0, 0);
        oacc[1][df] = __builtin_amdgcn_mfma_f32_16x16x32_bf16(pa[1][kk], vfr, oacc[1][df], 0, 0, 0);
      }
    }
    __builtin_amdgcn_s_setprio(0);
  }

  const int b = bh >> 4, h = bh & 15;
#pragma unroll
  for (int qf = 0; qf < 2; qf++) {
    float l = ls[qf];
    l += __shfl_xor(l, 16);
    l += __shfl_xor(l, 32);
    const float linv = 1.f / l;
    float iv[4];
#pragma unroll
    for (int r = 0; r < 4; r++) iv[r] = __shfl(linv, lk * 4 + r);
#pragma unroll
    for (int df = 0; df < 4; df++)
#pragma unroll
      for (int r = 0; r < 4; r++) {
        const int n = qt * 128 + w * 32 + qf * 16 + lk * 4 + r;
        O[((size_t)b * 2048 + n) * 1024 + h * 64 + df * 16 + lr] =
            f2b(oacc[qf][df][r] * iv[r]);
      }
  }
}

// ---------------- launcher ----------------
extern "C" void kernel_launch(void* const* d_in, const int* in_sizes, int n_in,
                              void* d_out, int out_size, void* d_ws, size_t ws_size,
                              hipStream_t stream) {
  const float* x  = (const float*)d_in[0];
  const float* Wq = (const float*)d_in[1];
  const float* Wk = (const float*)d_in[2];
  const float* Wv = (const float*)d_in[3];
  const float* Wo = (const float*)d_in[4];
  const float* bo = (const float*)d_in[5];
  float* out = (float*)d_out;

  u16* ws   = (u16*)d_ws;
  u16* xb   = ws;                  // 8192x1024 bf16; reused as attn_out after GEMM1
  u16* Wqkv = xb + 8388608;        // 3072x1024
  u16* Wob  = Wqkv + 3145728;      // 1024x1024
  u16* Qb   = Wob + 1048576;       // [b,h,n,d] (pre-scaled)
  u16* Kb   = Qb + 8388608;        // [b,h,n,d]
  u16* Vtb  = Kb + 8388608;        // [b,h,d,n'] (k-permuted)

  cvt4<<<8192, 256, 0, stream>>>(x, xb, 2097152);
  cvtW<<<4096, 256, 0, stream>>>(Wq, Wk, Wv, Wo, Wqkv, Wob);

  // QKV: C[8192x3072] = xb * Wqkv^T, routed into Q/K/Vt (256^2, 8-wave)
  gemm256<<<384, 512, 0, stream>>>(xb, Wqkv, Qb, Kb, Vtb);
  // attention -> xb as [b,n,h*64+d] bf16
  attn_fwd<<<1024, 256, 0, stream>>>(Qb, Kb, Vtb, xb);
  // out proj: fp32 out = xb * Wo^T + bo
  gemm_out<<<64 * 8, 256, 0, stream>>>(xb, Wob, 1024, 8, out, bo, 1024);
}